// Round 5
// baseline (145.063 us; speedup 1.0000x reference)
//
#include <hip/hip_runtime.h>

#define IN_F 1024
#define OUT_F 1024
#define NNZ 16384

typedef _Float16 f16;
typedef _Float16 f16x4 __attribute__((ext_vector_type(4)));
typedef _Float16 f16x8 __attribute__((ext_vector_type(8)));
typedef float f32x4 __attribute__((ext_vector_type(4)));
typedef unsigned short ushort8 __attribute__((ext_vector_type(8)));

#define AS1 __attribute__((address_space(1)))
#define AS3 __attribute__((address_space(3)))

// ---------------------------------------------------------------------------
// Workspace: S = staged W_eff (f16, 2 MiB) @0; mode flag (int) @2MiB.
// S layout (UNCHANGED from r2-r4, proven): tile t = g*16 + kt, g in [0,8)
// (128-row n-group), kt in [0,16) (64-k). 1024 slots x 16B per tile; slot
// s = r*8 + bb holds W_eff[g*128+r][kt*64 + ((bb^(r&7))<<3) .. +8].
// ---------------------------------------------------------------------------

__global__ void detect_mode(const unsigned short* __restrict__ w, int* __restrict__ mode) {
  __shared__ float smax[256];
  __shared__ int semax[256];
  int t = threadIdx.x;
  const float* wf = (const float*)w;
  float m32 = fabsf(wf[t]);
  m32 = fmaxf(m32, fabsf(wf[t + 256]));
  int e8 = 0;
#pragma unroll
  for (int j = 0; j < 8; ++j) {
    unsigned short u = w[t * 8 + j];
    int e = (u >> 7) & 0xFF;
    e8 = e > e8 ? e : e8;
  }
  smax[t] = m32; semax[t] = e8;
  __syncthreads();
  for (int s = 128; s > 0; s >>= 1) {
    if (t < s) {
      smax[t] = fmaxf(smax[t], smax[t + s]);
      semax[t] = semax[t] > semax[t + s] ? semax[t] : semax[t + s];
    }
    __syncthreads();
  }
  if (t == 0) {
    int m;
    if (!(smax[0] > 1e-6f)) m = 2;        // native f16
    else if (semax[0] >= 140) m = 0;      // f32 (upcast from fp16)
    else m = 1;                           // bf16
    *mode = m;
  }
}

__device__ __forceinline__ float load_w(const void* base, size_t i, int mode) {
  if (mode == 0) return ((const float*)base)[i];
  if (mode == 1) {
    unsigned int u = (unsigned int)((const unsigned short*)base)[i] << 16;
    return __uint_as_float(u);
  }
  return (float)((const f16*)base)[i];
}

__global__ void prep_base(const void* __restrict__ base, f16* __restrict__ S,
                          const int* __restrict__ modep) {
  int mode = *modep;
  int g = blockIdx.x * 256 + threadIdx.x;
  int tile = g >> 10;
  int s = g & 1023;
  int nt = tile >> 4, kt = tile & 15;
  int r = s >> 3, bb = s & 7;
  int n = nt * 128 + r;
  int k = kt * 64 + ((bb ^ (r & 7)) << 3);
  size_t off = (size_t)n * IN_F + k;
  f16x8 h;
  if (mode == 0) {
    const float* b = (const float*)base + off;
    float4 v0 = *reinterpret_cast<const float4*>(b);
    float4 v1 = *reinterpret_cast<const float4*>(b + 4);
    h = (f16x8){(f16)v0.x, (f16)v0.y, (f16)v0.z, (f16)v0.w,
                (f16)v1.x, (f16)v1.y, (f16)v1.z, (f16)v1.w};
  } else if (mode == 1) {
    ushort8 u = *reinterpret_cast<const ushort8*>((const unsigned short*)base + off);
#pragma unroll
    for (int j = 0; j < 8; ++j)
      h[j] = (f16)__uint_as_float((unsigned int)u[j] << 16);
  } else {
    h = *reinterpret_cast<const f16x8*>((const f16*)base + off);
  }
  *reinterpret_cast<f16x8*>(S + (size_t)g * 8) = h;
}

__global__ void prep_scatter(const void* __restrict__ base,
                             const void* __restrict__ vals,
                             const int* __restrict__ idx,
                             const float* __restrict__ alpha,
                             f16* __restrict__ S,
                             const int* __restrict__ modep) {
  int mode = *modep;
  int i = blockIdx.x * 256 + threadIdx.x;
  if (i >= NNZ) return;
  int id = idx[i];
  int n = id >> 10, k = id & 1023;
  float v = load_w(base, id, mode) + alpha[0] * load_w(vals, i, mode);
  int nt = n >> 7, r = n & 127;
  int kt = k >> 6, kk = k & 63;
  int b = kk >> 3, e = kk & 7;
  int slot = (r << 3) | (b ^ (r & 7));
  size_t pos = ((size_t)((nt * 16 + kt) * 1024 + slot)) * 8 + (size_t)e;
  S[pos] = (f16)v;
}

// ---------------------------------------------------------------------------
// 8-phase 256x256 GEMM (m201 template port). BK=64, 512 thr = 8 waves (2Mx4N),
// wave tile 128x64. LDS 128 KiB dynamic: sA[2buf][2half][128][64] f16 (64KB) +
// sB same (64KB). Per K-tile kt (buffer P=kt&1): 4 phases (q,s) =
// (0,0),(1,0),(0,1),(1,1), each {ds_read frags; stage-op; barrier; lgkm(0);
// setprio(1); 16 MFMA; setprio(0); barrier}. Stages target kt+1 / buffer P^1:
//   ph0: issue A-half0 (4xfloat4) + B-half0 (2x global_load_lds)
//   ph1: issue A-half1 + B-half1
//   ph2: vmcnt(8) -> cvt+ds_write A-half0
//   ph3: vmcnt(2) -> cvt+ds_write A-half1; vmcnt(0) before publish barrier.
// vmcnt never 0 except once per K-tile (publish). Correctness is independent
// of count accuracy: A-reg reads are compiler-tracked; B publish guarded by
// the absolute vmcnt(0)+barrier.
// ---------------------------------------------------------------------------

#define SB0 __builtin_amdgcn_sched_barrier(0)
#define VMW(N) asm volatile("s_waitcnt vmcnt(" #N ")" ::: "memory")

#define ISSUE_AX(H, KT1) do {                                                  \
    _Pragma("unroll")                                                          \
    for (int j_ = 0; j_ < 4; ++j_)                                             \
      arA##H[j_] = *reinterpret_cast<const float4*>(                           \
          Xg + (size_t)(H) * 131072 + goffA[j_] + (KT1) * 64);                 \
  } while (0)

#define ISSUE_BW(H, KT1, PB) do {                                              \
    _Pragma("unroll")                                                          \
    for (int c_ = 0; c_ < 2; ++c_) {                                           \
      int slot_ = c_ * 512 + t;                                                \
      __builtin_amdgcn_global_load_lds(                                        \
          (const AS1 void*)(Swz + ((size_t)((nt * 2 + (H)) * 16 + (KT1))) * 8192 + slot_ * 8), \
          (AS3 void*)(&sB[((PB) * 2 + (H)) * 8192 + slot_ * 8]), 16, 0, 0);    \
    }                                                                          \
  } while (0)

#define CVT_WRITE(H, PB) do {                                                  \
    _Pragma("unroll")                                                          \
    for (int j_ = 0; j_ < 4; ++j_) {                                           \
      float4 v_ = arA##H[j_];                                                  \
      f16x4 h_ = {(f16)v_.x, (f16)v_.y, (f16)v_.z, (f16)v_.w};                 \
      *reinterpret_cast<f16x4*>(&sA[((PB) * 2 + (H)) * 8192 + hioA[j_]]) = h_; \
    }                                                                          \
  } while (0)

#define PHASE(P, Q, S_, LOADB, STG) do {                                       \
    int aoff_ = ((P) * 2 + wm) * 8192;                                         \
    _Pragma("unroll")                                                          \
    for (int mf_ = 0; mf_ < 4; ++mf_) {                                        \
      int r_ = (Q) * 64 + mf_ * 16 + lr;                                       \
      int blk_ = ((S_) * 4 + lk) ^ (lr & 7);                                   \
      afr[mf_] = *reinterpret_cast<const f16x8*>(&sA[aoff_ + r_ * 64 + blk_ * 8]); \
    }                                                                          \
    if (LOADB) {                                                               \
      int boff_ = ((P) * 2 + bh) * 8192;                                       \
      _Pragma("unroll")                                                        \
      for (int nf_ = 0; nf_ < 4; ++nf_) {                                      \
        int r_ = bro + nf_ * 16 + lr;                                          \
        int blk_ = ((S_) * 4 + lk) ^ (lr & 7);                                 \
        bfr[nf_] = *reinterpret_cast<const f16x8*>(&sB[boff_ + r_ * 64 + blk_ * 8]); \
      }                                                                        \
    }                                                                          \
    STG;                                                                       \
    SB0;                                                                       \
    __builtin_amdgcn_s_barrier();                                              \
    asm volatile("s_waitcnt lgkmcnt(0)" ::: "memory");                         \
    SB0;                                                                       \
    __builtin_amdgcn_s_setprio(1);                                             \
    _Pragma("unroll")                                                          \
    for (int mf_ = 0; mf_ < 4; ++mf_)                                          \
      _Pragma("unroll")                                                        \
      for (int nf_ = 0; nf_ < 4; ++nf_)                                        \
        acc[(Q) * 4 + mf_][nf_] = __builtin_amdgcn_mfma_f32_16x16x32_f16(      \
            afr[mf_], bfr[nf_], acc[(Q) * 4 + mf_][nf_], 0, 0, 0);             \
    __builtin_amdgcn_s_setprio(0);                                             \
    __builtin_amdgcn_s_barrier();                                              \
    SB0;                                                                       \
  } while (0)

#define KTILE(P, KT, PREF) do {                                                \
    PHASE(P, 0, 0, true,                                                       \
          { if (PREF) { ISSUE_AX(0, (KT) + 1); SB0; ISSUE_BW(0, (KT) + 1, (P) ^ 1); } }); \
    PHASE(P, 1, 0, false,                                                      \
          { if (PREF) { ISSUE_AX(1, (KT) + 1); SB0; ISSUE_BW(1, (KT) + 1, (P) ^ 1); } }); \
    PHASE(P, 0, 1, true,                                                       \
          { if (PREF) { VMW(8); CVT_WRITE(0, (P) ^ 1); } });                   \
    PHASE(P, 1, 1, false,                                                      \
          { if (PREF) { VMW(2); CVT_WRITE(1, (P) ^ 1); VMW(0); } });           \
  } while (0)

__global__ void __launch_bounds__(512, 2) gemm_kernel(const float* __restrict__ X,
                                                      const f16* __restrict__ Swz,
                                                      float* __restrict__ C) {
  extern __shared__ f16 lds[];
  f16* sA = lds;            // 2buf x 2half x 128 x 64 = 32768 f16
  f16* sB = lds + 32768;

  // bijective XCD swizzle; grid = 512 (128 mt x 4 nt), q = 64
  int bidx = blockIdx.x;
  int wg = (bidx & 7) * 64 + (bidx >> 3);
  int mt = wg >> 2, nt = wg & 3;

  int t = threadIdx.x;
  int lane = t & 63;
  int w = t >> 6;
  int wm = w >> 2;           // 0..1 : M half (128 rows)
  int wn = w & 3;            // 0..3 : N quarter (64 cols)
  int lr = lane & 15;
  int lk = lane >> 4;
  int bh = wn >> 1;          // B half for this wave's columns
  int bro = (wn & 1) * 64;   // row offset within B half

  const float* Xg = X + (size_t)mt * 256 * IN_F;

  // staging geometry: A half-tile = 128x64 fp32; thread covers 4 float4
  int goffA[4], hioA[4];
#pragma unroll
  for (int j = 0; j < 4; ++j) {
    int f = t + j * 512;
    int r = f >> 4, c4 = f & 15;
    goffA[j] = r * IN_F + c4 * 4;
    hioA[j] = r * 64 + ((((c4 >> 1) ^ (r & 7)) << 3) + ((c4 & 1) << 2));
  }

  float4 arA0[4], arA1[4];
  f16x8 afr[4], bfr[4];
  f32x4 acc[8][4];
#pragma unroll
  for (int i = 0; i < 8; ++i)
#pragma unroll
    for (int j = 0; j < 4; ++j)
      acc[i][j] = (f32x4){0.f, 0.f, 0.f, 0.f};

  // prologue: fill buffer 0 with kt=0
  ISSUE_AX(0, 0); SB0; ISSUE_BW(0, 0, 0); SB0;
  ISSUE_AX(1, 0); SB0; ISSUE_BW(1, 0, 0); SB0;
  VMW(8); CVT_WRITE(0, 0);
  VMW(2); CVT_WRITE(1, 0); VMW(0);
  asm volatile("s_waitcnt lgkmcnt(0)" ::: "memory");
  __builtin_amdgcn_s_barrier();
  SB0;

  for (int kt2 = 0; kt2 < 14; kt2 += 2) {
    KTILE(0, kt2, true);
    KTILE(1, kt2 + 1, true);
  }
  KTILE(0, 14, true);
  KTILE(1, 15, false);

  // epilogue: acc[m][nf], m = q*4+mf -> row (m>>2)*64 + (m&3)*16
  float* Cw = C + (size_t)(mt * 256 + wm * 128 + lk * 4) * OUT_F + nt * 256 + wn * 64 + lr;
#pragma unroll
  for (int m = 0; m < 8; ++m) {
    int rowo = (m >> 2) * 64 + (m & 3) * 16;
#pragma unroll
    for (int nf = 0; nf < 4; ++nf)
#pragma unroll
      for (int g = 0; g < 4; ++g)
        Cw[(size_t)(rowo + g) * OUT_F + nf * 16] = acc[m][nf][g];
  }
}

extern "C" void kernel_launch(void* const* d_in, const int* in_sizes, int n_in,
                              void* d_out, int out_size, void* d_ws, size_t ws_size,
                              hipStream_t stream) {
  const float* X = (const float*)d_in[0];
  const void* base = d_in[1];
  const void* vals = d_in[2];
  const int* idx = (const int*)d_in[3];
  const float* alpha = (const float*)d_in[4];
  float* out = (float*)d_out;
  f16* S = (f16*)d_ws;                                    // 2 MiB staged W
  int* modep = (int*)((char*)d_ws + 2 * 1024 * 1024);     // mode flag

  int M = in_sizes[0] / IN_F;              // 32768
  int mtiles = M / 256;                    // 128

  (void)hipFuncSetAttribute(reinterpret_cast<const void*>(gemm_kernel),
                            hipFuncAttributeMaxDynamicSharedMemorySize, 131072);

  detect_mode<<<dim3(1), dim3(256), 0, stream>>>((const unsigned short*)base, modep);
  prep_base<<<dim3((OUT_F * IN_F / 8) / 256), dim3(256), 0, stream>>>(base, S, modep);
  prep_scatter<<<dim3((NNZ + 255) / 256), dim3(256), 0, stream>>>(base, vals, idx, alpha, S, modep);
  gemm_kernel<<<dim3(mtiles * 4), dim3(512), 131072, stream>>>(X, S, out);
}

// Round 6
// 131.393 us; speedup vs baseline: 1.1040x; 1.1040x over previous
//
#include <hip/hip_runtime.h>

#define IN_F 1024
#define OUT_F 1024
#define NNZ 16384

typedef _Float16 f16;
typedef _Float16 f16x4 __attribute__((ext_vector_type(4)));
typedef _Float16 f16x8 __attribute__((ext_vector_type(8)));
typedef float f32x4 __attribute__((ext_vector_type(4)));
typedef unsigned short ushort8 __attribute__((ext_vector_type(8)));

#define AS1 __attribute__((address_space(1)))
#define AS3 __attribute__((address_space(3)))

// ---------------------------------------------------------------------------
// Workspace: S = staged W_eff (f16, 2 MiB) @0; mode flag @2MiB; Xs = staged
// f16 X @2MiB+4096 (64 MB, only if ws_size permits).
// Staged layout (both S and Xs): group g (128 rows), kt (64-k). Tile(g,kt) =
// 1024 slots x 16B; slot s = r*8+bb holds M[g*128+r][kt*64 + ((bb^(r&7))<<3)..+8].
// GEMM DMA-stages slots linearly (global_load_lds) and reads with the same XOR
// -> conflict-free, data correct (G21 both-sides rule).
// ---------------------------------------------------------------------------

__global__ void detect_mode(const unsigned short* __restrict__ w, int* __restrict__ mode) {
  __shared__ float smax[256];
  __shared__ int semax[256];
  int t = threadIdx.x;
  const float* wf = (const float*)w;
  float m32 = fabsf(wf[t]);
  m32 = fmaxf(m32, fabsf(wf[t + 256]));
  int e8 = 0;
#pragma unroll
  for (int j = 0; j < 8; ++j) {
    unsigned short u = w[t * 8 + j];
    int e = (u >> 7) & 0xFF;
    e8 = e > e8 ? e : e8;
  }
  smax[t] = m32; semax[t] = e8;
  __syncthreads();
  for (int s = 128; s > 0; s >>= 1) {
    if (t < s) {
      smax[t] = fmaxf(smax[t], smax[t + s]);
      semax[t] = semax[t] > semax[t + s] ? semax[t] : semax[t + s];
    }
    __syncthreads();
  }
  if (t == 0) {
    int m;
    if (!(smax[0] > 1e-6f)) m = 2;        // native f16
    else if (semax[0] >= 140) m = 0;      // f32 (upcast from fp16)
    else m = 1;                           // bf16
    *mode = m;
  }
}

__device__ __forceinline__ float load_w(const void* base, size_t i, int mode) {
  if (mode == 0) return ((const float*)base)[i];
  if (mode == 1) {
    unsigned int u = (unsigned int)((const unsigned short*)base)[i] << 16;
    return __uint_as_float(u);
  }
  return (float)((const f16*)base)[i];
}

__global__ void prep_base(const void* __restrict__ base, f16* __restrict__ S,
                          const int* __restrict__ modep) {
  int mode = *modep;
  int g = blockIdx.x * 256 + threadIdx.x;
  int tile = g >> 10;
  int s = g & 1023;
  int nt = tile >> 4, kt = tile & 15;
  int r = s >> 3, bb = s & 7;
  int n = nt * 128 + r;
  int k = kt * 64 + ((bb ^ (r & 7)) << 3);
  size_t off = (size_t)n * IN_F + k;
  f16x8 h;
  if (mode == 0) {
    const float* b = (const float*)base + off;
    float4 v0 = *reinterpret_cast<const float4*>(b);
    float4 v1 = *reinterpret_cast<const float4*>(b + 4);
    h = (f16x8){(f16)v0.x, (f16)v0.y, (f16)v0.z, (f16)v0.w,
                (f16)v1.x, (f16)v1.y, (f16)v1.z, (f16)v1.w};
  } else if (mode == 1) {
    ushort8 u = *reinterpret_cast<const ushort8*>((const unsigned short*)base + off);
#pragma unroll
    for (int j = 0; j < 8; ++j)
      h[j] = (f16)__uint_as_float((unsigned int)u[j] << 16);
  } else {
    h = *reinterpret_cast<const f16x8*>((const f16*)base + off);
  }
  *reinterpret_cast<f16x8*>(S + (size_t)g * 8) = h;
}

__global__ void prep_scatter(const void* __restrict__ base,
                             const void* __restrict__ vals,
                             const int* __restrict__ idx,
                             const float* __restrict__ alpha,
                             f16* __restrict__ S,
                             const int* __restrict__ modep) {
  int mode = *modep;
  int i = blockIdx.x * 256 + threadIdx.x;
  if (i >= NNZ) return;
  int id = idx[i];
  int n = id >> 10, k = id & 1023;
  float v = load_w(base, id, mode) + alpha[0] * load_w(vals, i, mode);
  int nt = n >> 7, r = n & 127;
  int kt = k >> 6, kk = k & 63;
  int b = kk >> 3, e = kk & 7;
  int slot = (r << 3) | (b ^ (r & 7));
  size_t pos = ((size_t)((nt * 16 + kt) * 1024 + slot)) * 8 + (size_t)e;
  S[pos] = (f16)v;
}

// Convert X (fp32, row-major) into staged pre-swizzled f16 layout Xs.
__global__ void __launch_bounds__(256) conv_x(const float* __restrict__ X,
                                              f16* __restrict__ Xs) {
  int id = blockIdx.x * 256 + threadIdx.x;    // slot id
  int s = id & 1023;
  int kt = (id >> 10) & 15;
  int g = id >> 14;
  int r = s >> 3, bb = s & 7;
  size_t row = (size_t)g * 128 + r;
  int k = kt * 64 + ((bb ^ (r & 7)) << 3);
  const float* p = X + row * IN_F + k;
  float4 v0 = *reinterpret_cast<const float4*>(p);
  float4 v1 = *reinterpret_cast<const float4*>(p + 4);
  f16x8 h = {(f16)v0.x, (f16)v0.y, (f16)v0.z, (f16)v0.w,
             (f16)v1.x, (f16)v1.y, (f16)v1.z, (f16)v1.w};
  *reinterpret_cast<f16x8*>(Xs + (size_t)id * 8) = h;
}

#define SB0 __builtin_amdgcn_sched_barrier(0)
#define VMW(N) asm volatile("s_waitcnt vmcnt(" #N ")" ::: "memory")

// ---------------------------------------------------------------------------
// gemm2: pure-DMA 256x256 8-phase GEMM. Both operands f16, staged via
// global_load_lds (8 x 16B per thread per K-tile, all issued at ph0 for KT+1,
// 3-phase flight, single VMW(0) publish gate at ph3). No reg-staging.
// ---------------------------------------------------------------------------

#define ISSUE_AB(KT1, PB) do {                                                 \
    _Pragma("unroll")                                                          \
    for (int c_ = 0; c_ < 2; ++c_) {                                           \
      int slot_ = c_ * 512 + t;                                                \
      _Pragma("unroll")                                                        \
      for (int h_ = 0; h_ < 2; ++h_) {                                         \
        __builtin_amdgcn_global_load_lds(                                      \
            (const AS1 void*)(Xs + ((size_t)((2 * mt + h_) * 16 + (KT1))) * 8192 + slot_ * 8), \
            (AS3 void*)(&sA[((PB) * 2 + h_) * 8192 + slot_ * 8]), 16, 0, 0);   \
        __builtin_amdgcn_global_load_lds(                                      \
            (const AS1 void*)(Swz + ((size_t)((nt * 2 + h_) * 16 + (KT1))) * 8192 + slot_ * 8), \
            (AS3 void*)(&sB[((PB) * 2 + h_) * 8192 + slot_ * 8]), 16, 0, 0);   \
      }                                                                        \
    }                                                                          \
  } while (0)

#define PHASE2(P, Q, S_, LOADB, STG) do {                                      \
    int aoff_ = ((P) * 2 + wm) * 8192;                                         \
    _Pragma("unroll")                                                          \
    for (int mf_ = 0; mf_ < 4; ++mf_) {                                        \
      int r_ = (Q) * 64 + mf_ * 16 + lr;                                       \
      int blk_ = ((S_) * 4 + lk) ^ (lr & 7);                                   \
      afr[mf_] = *reinterpret_cast<const f16x8*>(&sA[aoff_ + r_ * 64 + blk_ * 8]); \
    }                                                                          \
    if (LOADB) {                                                               \
      int boff_ = ((P) * 2 + bh) * 8192;                                       \
      _Pragma("unroll")                                                        \
      for (int nf_ = 0; nf_ < 4; ++nf_) {                                      \
        int r_ = bro + nf_ * 16 + lr;                                          \
        int blk_ = ((S_) * 4 + lk) ^ (lr & 7);                                 \
        bfr[nf_] = *reinterpret_cast<const f16x8*>(&sB[boff_ + r_ * 64 + blk_ * 8]); \
      }                                                                        \
    }                                                                          \
    STG;                                                                       \
    SB0;                                                                       \
    __builtin_amdgcn_s_barrier();                                              \
    asm volatile("s_waitcnt lgkmcnt(0)" ::: "memory");                         \
    SB0;                                                                       \
    __builtin_amdgcn_s_setprio(1);                                             \
    _Pragma("unroll")                                                          \
    for (int mf_ = 0; mf_ < 4; ++mf_)                                          \
      _Pragma("unroll")                                                        \
      for (int nf_ = 0; nf_ < 4; ++nf_)                                        \
        acc[(Q) * 4 + mf_][nf_] = __builtin_amdgcn_mfma_f32_16x16x32_f16(      \
            afr[mf_], bfr[nf_], acc[(Q) * 4 + mf_][nf_], 0, 0, 0);             \
    __builtin_amdgcn_s_setprio(0);                                             \
    __builtin_amdgcn_s_barrier();                                              \
    SB0;                                                                       \
  } while (0)

#define KTILE2(P, KT, PREF) do {                                               \
    PHASE2(P, 0, 0, true,  { if (PREF) { ISSUE_AB((KT) + 1, (P) ^ 1); } });    \
    PHASE2(P, 1, 0, false, {});                                                \
    PHASE2(P, 0, 1, true,  {});                                                \
    PHASE2(P, 1, 1, false, { VMW(0); });                                       \
  } while (0)

__global__ void __launch_bounds__(512, 2) gemm2(const f16* __restrict__ Xs,
                                                const f16* __restrict__ Swz,
                                                float* __restrict__ C) {
  extern __shared__ f16 lds[];
  f16* sA = lds;            // [2buf][2half][8192]
  f16* sB = lds + 32768;

  int bidx = blockIdx.x;
  int q = gridDim.x >> 3;
  int wg = (bidx & 7) * q + (bidx >> 3);
  int mt = wg >> 2, nt = wg & 3;

  int t = threadIdx.x;
  int lane = t & 63;
  int w = t >> 6;
  int wm = w >> 2;           // M half (128 rows)
  int wn = w & 3;            // N quarter (64 cols)
  int lr = lane & 15;
  int lk = lane >> 4;
  int bh = wn >> 1;
  int bro = (wn & 1) * 64;

  f16x8 afr[4], bfr[4];
  f32x4 acc[8][4];
#pragma unroll
  for (int i = 0; i < 8; ++i)
#pragma unroll
    for (int j = 0; j < 4; ++j)
      acc[i][j] = (f32x4){0.f, 0.f, 0.f, 0.f};

  // prologue: fill buffer 0 with kt=0
  ISSUE_AB(0, 0);
  VMW(0);
  __builtin_amdgcn_s_barrier();
  SB0;

  for (int kt2 = 0; kt2 < 14; kt2 += 2) {
    KTILE2(0, kt2, true);
    KTILE2(1, kt2 + 1, true);
  }
  KTILE2(0, 14, true);
  KTILE2(1, 15, false);

  float* Cw = C + (size_t)(mt * 256 + wm * 128 + lk * 4) * OUT_F + nt * 256 + wn * 64 + lr;
#pragma unroll
  for (int m = 0; m < 8; ++m) {
    int rowo = (m >> 2) * 64 + (m & 3) * 16;
#pragma unroll
    for (int nf = 0; nf < 4; ++nf)
#pragma unroll
      for (int g = 0; g < 4; ++g)
        Cw[(size_t)(rowo + g) * OUT_F + nf * 16] = acc[m][nf][g];
  }
}

// ---------------------------------------------------------------------------
// Fallback (round-5 kernel, fp32-A reg-staged): used only if ws too small.
// ---------------------------------------------------------------------------

#define ISSUE_AX(H, KT1) do {                                                  \
    _Pragma("unroll")                                                          \
    for (int j_ = 0; j_ < 4; ++j_)                                             \
      arA##H[j_] = *reinterpret_cast<const float4*>(                           \
          Xg + (size_t)(H) * 131072 + goffA[j_] + (KT1) * 64);                 \
  } while (0)

#define ISSUE_BW(H, KT1, PB) do {                                              \
    _Pragma("unroll")                                                          \
    for (int c_ = 0; c_ < 2; ++c_) {                                           \
      int slot_ = c_ * 512 + t;                                                \
      __builtin_amdgcn_global_load_lds(                                        \
          (const AS1 void*)(Swz + ((size_t)((nt * 2 + (H)) * 16 + (KT1))) * 8192 + slot_ * 8), \
          (AS3 void*)(&sB[((PB) * 2 + (H)) * 8192 + slot_ * 8]), 16, 0, 0);    \
    }                                                                          \
  } while (0)

#define CVT_WRITE(H, PB) do {                                                  \
    _Pragma("unroll")                                                          \
    for (int j_ = 0; j_ < 4; ++j_) {                                           \
      float4 v_ = arA##H[j_];                                                  \
      f16x4 h_ = {(f16)v_.x, (f16)v_.y, (f16)v_.z, (f16)v_.w};                 \
      *reinterpret_cast<f16x4*>(&sA[((PB) * 2 + (H)) * 8192 + hioA[j_]]) = h_; \
    }                                                                          \
  } while (0)

#define PHASE(P, Q, S_, LOADB, STG) do {                                       \
    int aoff_ = ((P) * 2 + wm) * 8192;                                         \
    _Pragma("unroll")                                                          \
    for (int mf_ = 0; mf_ < 4; ++mf_) {                                        \
      int r_ = (Q) * 64 + mf_ * 16 + lr;                                       \
      int blk_ = ((S_) * 4 + lk) ^ (lr & 7);                                   \
      afr[mf_] = *reinterpret_cast<const f16x8*>(&sA[aoff_ + r_ * 64 + blk_ * 8]); \
    }                                                                          \
    if (LOADB) {                                                               \
      int boff_ = ((P) * 2 + bh) * 8192;                                       \
      _Pragma("unroll")                                                        \
      for (int nf_ = 0; nf_ < 4; ++nf_) {                                      \
        int r_ = bro + nf_ * 16 + lr;                                          \
        int blk_ = ((S_) * 4 + lk) ^ (lr & 7);                                 \
        bfr[nf_] = *reinterpret_cast<const f16x8*>(&sB[boff_ + r_ * 64 + blk_ * 8]); \
      }                                                                        \
    }                                                                          \
    STG;                                                                       \
    SB0;                                                                       \
    __builtin_amdgcn_s_barrier();                                              \
    asm volatile("s_waitcnt lgkmcnt(0)" ::: "memory");                         \
    SB0;                                                                       \
    __builtin_amdgcn_s_setprio(1);                                             \
    _Pragma("unroll")                                                          \
    for (int mf_ = 0; mf_ < 4; ++mf_)                                          \
      _Pragma("unroll")                                                        \
      for (int nf_ = 0; nf_ < 4; ++nf_)                                        \
        acc[(Q) * 4 + mf_][nf_] = __builtin_amdgcn_mfma_f32_16x16x32_f16(      \
            afr[mf_], bfr[nf_], acc[(Q) * 4 + mf_][nf_], 0, 0, 0);             \
    __builtin_amdgcn_s_setprio(0);                                             \
    __builtin_amdgcn_s_barrier();                                              \
    SB0;                                                                       \
  } while (0)

#define KTILE(P, KT, PREF) do {                                                \
    PHASE(P, 0, 0, true,                                                       \
          { if (PREF) { ISSUE_AX(0, (KT) + 1); SB0; ISSUE_BW(0, (KT) + 1, (P) ^ 1); } }); \
    PHASE(P, 1, 0, false,                                                      \
          { if (PREF) { ISSUE_AX(1, (KT) + 1); SB0; ISSUE_BW(1, (KT) + 1, (P) ^ 1); } }); \
    PHASE(P, 0, 1, true,                                                       \
          { if (PREF) { VMW(8); CVT_WRITE(0, (P) ^ 1); } });                   \
    PHASE(P, 1, 1, false,                                                      \
          { if (PREF) { VMW(2); CVT_WRITE(1, (P) ^ 1); VMW(0); } });           \
  } while (0)

__global__ void __launch_bounds__(512, 2) gemm_kernel(const float* __restrict__ X,
                                                      const f16* __restrict__ Swz,
                                                      float* __restrict__ C) {
  extern __shared__ f16 lds[];
  f16* sA = lds;
  f16* sB = lds + 32768;

  int bidx = blockIdx.x;
  int q = gridDim.x >> 3;
  int wg = (bidx & 7) * q + (bidx >> 3);
  int mt = wg >> 2, nt = wg & 3;

  int t = threadIdx.x;
  int lane = t & 63;
  int w = t >> 6;
  int wm = w >> 2;
  int wn = w & 3;
  int lr = lane & 15;
  int lk = lane >> 4;
  int bh = wn >> 1;
  int bro = (wn & 1) * 64;

  const float* Xg = X + (size_t)mt * 256 * IN_F;

  int goffA[4], hioA[4];
#pragma unroll
  for (int j = 0; j < 4; ++j) {
    int f = t + j * 512;
    int r = f >> 4, c4 = f & 15;
    goffA[j] = r * IN_F + c4 * 4;
    hioA[j] = r * 64 + ((((c4 >> 1) ^ (r & 7)) << 3) + ((c4 & 1) << 2));
  }

  float4 arA0[4], arA1[4];
  f16x8 afr[4], bfr[4];
  f32x4 acc[8][4];
#pragma unroll
  for (int i = 0; i < 8; ++i)
#pragma unroll
    for (int j = 0; j < 4; ++j)
      acc[i][j] = (f32x4){0.f, 0.f, 0.f, 0.f};

  ISSUE_AX(0, 0); SB0; ISSUE_BW(0, 0, 0); SB0;
  ISSUE_AX(1, 0); SB0; ISSUE_BW(1, 0, 0); SB0;
  VMW(8); CVT_WRITE(0, 0);
  VMW(2); CVT_WRITE(1, 0); VMW(0);
  asm volatile("s_waitcnt lgkmcnt(0)" ::: "memory");
  __builtin_amdgcn_s_barrier();
  SB0;

  for (int kt2 = 0; kt2 < 14; kt2 += 2) {
    KTILE(0, kt2, true);
    KTILE(1, kt2 + 1, true);
  }
  KTILE(0, 14, true);
  KTILE(1, 15, false);

  float* Cw = C + (size_t)(mt * 256 + wm * 128 + lk * 4) * OUT_F + nt * 256 + wn * 64 + lr;
#pragma unroll
  for (int m = 0; m < 8; ++m) {
    int rowo = (m >> 2) * 64 + (m & 3) * 16;
#pragma unroll
    for (int nf = 0; nf < 4; ++nf)
#pragma unroll
      for (int g = 0; g < 4; ++g)
        Cw[(size_t)(rowo + g) * OUT_F + nf * 16] = acc[m][nf][g];
  }
}

extern "C" void kernel_launch(void* const* d_in, const int* in_sizes, int n_in,
                              void* d_out, int out_size, void* d_ws, size_t ws_size,
                              hipStream_t stream) {
  const float* X = (const float*)d_in[0];
  const void* base = d_in[1];
  const void* vals = d_in[2];
  const int* idx = (const int*)d_in[3];
  const float* alpha = (const float*)d_in[4];
  float* out = (float*)d_out;
  f16* S = (f16*)d_ws;
  int* modep = (int*)((char*)d_ws + 2 * 1024 * 1024);
  f16* Xs = (f16*)((char*)d_ws + 2 * 1024 * 1024 + 4096);

  int M = in_sizes[0] / IN_F;              // 32768
  size_t need = 2 * 1024 * 1024 + 4096 + (size_t)M * IN_F * sizeof(f16);

  (void)hipFuncSetAttribute(reinterpret_cast<const void*>(&gemm2),
                            hipFuncAttributeMaxDynamicSharedMemorySize, 131072);
  (void)hipFuncSetAttribute(reinterpret_cast<const void*>(&gemm_kernel),
                            hipFuncAttributeMaxDynamicSharedMemorySize, 131072);

  detect_mode<<<dim3(1), dim3(256), 0, stream>>>((const unsigned short*)base, modep);
  prep_base<<<dim3((OUT_F * IN_F / 8) / 256), dim3(256), 0, stream>>>(base, S, modep);
  prep_scatter<<<dim3((NNZ + 255) / 256), dim3(256), 0, stream>>>(base, vals, idx, alpha, S, modep);

  if (ws_size >= need) {
    conv_x<<<dim3((M / 128) * 64), dim3(256), 0, stream>>>(X, Xs);
    gemm2<<<dim3((M / 256) * 4), dim3(512), 131072, stream>>>(Xs, S, out);
  } else {
    // fallback marker: old kernel twice (idempotent) -> distinctive headline
    gemm_kernel<<<dim3((M / 256) * 4), dim3(512), 131072, stream>>>(X, S, out);
    gemm_kernel<<<dim3((M / 256) * 4), dim3(512), 131072, stream>>>(X, S, out);
  }
}